// Round 1
// baseline (913.715 us; speedup 1.0000x reference)
//
#include <hip/hip_runtime.h>

// RNN scan: B=2048, T=512, V=64, H=256, K=H+V=320.
// 128 persistent blocks x 256 threads (4 waves). Each block owns 16 batch rows
// for all 512 steps. Theta lives in VGPRs as MFMA B-fragments (loaded once).
// State double-buffered in LDS as bf16 in A-fragment-friendly row-major layout.
// Tokens stream global->VGPR in A-frag layout, prefetched one step ahead.
// bias input provably cancels in LayerNorm -> unused.

#define TT 512
#define VV 64
#define HH 256
#define STRD 264   // ushorts per state row: 256 + 8 pad (33 x 16B -> conflict-free b128)

typedef short bf16x8 __attribute__((ext_vector_type(8)));
typedef float f32x4  __attribute__((ext_vector_type(4)));

__device__ __forceinline__ unsigned short f2bf(float f) {
    unsigned int u = __float_as_uint(f);
    unsigned int r = (u + 0x7fffu + ((u >> 16) & 1u)) >> 16;   // RNE
    return (unsigned short)r;
}

__device__ __forceinline__ float bf2f(unsigned short u) {
    return __uint_as_float(((unsigned int)u) << 16);
}

__device__ __forceinline__ bf16x8 pack8(float4 a, float4 b) {
    bf16x8 v;
    v[0] = (short)f2bf(a.x); v[1] = (short)f2bf(a.y);
    v[2] = (short)f2bf(a.z); v[3] = (short)f2bf(a.w);
    v[4] = (short)f2bf(b.x); v[5] = (short)f2bf(b.y);
    v[6] = (short)f2bf(b.z); v[7] = (short)f2bf(b.w);
    return v;
}

// x += dpp_perm(x); CTRL compile-time. VALU pipe (keeps LDS pipe free for A-frags).
template <int CTRL>
__device__ __forceinline__ float dppadd(float x) {
    int y = __builtin_amdgcn_update_dpp(0, __float_as_int(x), CTRL, 0xF, 0xF, false);
    return x + __int_as_float(y);
}

extern "C" __global__ void __launch_bounds__(256, 1)
rnn_scan_kernel(const float* __restrict__ seq,        // [2048][512][64]
                const float* __restrict__ theta,      // [256][320]
                const float* __restrict__ theta_dot,  // [256]
                float* __restrict__ out)              // [2048]
{
    __shared__ unsigned short stbuf[2][16][STRD];   // state, bf16, double-buffered
    __shared__ float2 partials[64];                 // [row 0..15][wave 0..3] (sum, sumsq)

    const int tid = threadIdx.x;
    const int w   = tid >> 6;        // wave 0..3  -> N columns [64w, 64w+64)
    const int l   = tid & 63;        // lane
    const int q   = l >> 4;          // quad-row group 0..3
    const int loc = l & 15;
    const int r0  = blockIdx.x << 4; // first batch row of this block

    // ---- Theta -> resident B-fragments: bfrag[ks][s] covers K [32ks,32ks+32) x N [64w+16s, +16)
    // B-frag layout: lane holds B[k = q*8+j][n = loc], i.e. theta[n][k..k+7] (contiguous).
    bf16x8 bfrag[10][4];
#pragma unroll
    for (int s = 0; s < 4; ++s) {
        const float* trow = theta + (size_t)(w * 64 + s * 16 + loc) * 320;
#pragma unroll
        for (int ks = 0; ks < 10; ++ks) {
            float4 f0 = *(const float4*)(trow + ks * 32 + q * 8);
            float4 f1 = *(const float4*)(trow + ks * 32 + q * 8 + 4);
            bfrag[ks][s] = pack8(f0, f1);
        }
    }

    // ---- zero initial state (buffer 0) ----
    {
        const int m = tid >> 4, c = (tid & 15) * 16;
        uint4 z = make_uint4(0u, 0u, 0u, 0u);
        *(uint4*)(&stbuf[0][m][c])     = z;
        *(uint4*)(&stbuf[0][m][c + 8]) = z;
    }

    // ---- prefetch token t=0 in A-frag layout: lane = row loc, features q*8.. ----
    const float* srow = seq + (size_t)(r0 + loc) * (TT * VV);
    float4 tk0 = *(const float4*)(srow + q * 8);
    float4 tk1 = *(const float4*)(srow + q * 8 + 4);
    float4 tk2 = *(const float4*)(srow + 32 + q * 8);
    float4 tk3 = *(const float4*)(srow + 32 + q * 8 + 4);

    __syncthreads();

#pragma unroll 1
    for (int t = 0; t < TT; ++t) {
        unsigned short* stc = &stbuf[t & 1][0][0];
        unsigned short* stn = &stbuf[(t + 1) & 1][0][0];

        // token A-frags for this step (K blocks 8,9 = features 0..31 / 32..63)
        bf16x8 a8 = pack8(tk0, tk1);
        bf16x8 a9 = pack8(tk2, tk3);

        // prefetch next step's token (covered by this whole step's latency)
        if (t + 1 < TT) {
            const float* p = srow + (size_t)(t + 1) * VV;
            tk0 = *(const float4*)(p + q * 8);
            tk1 = *(const float4*)(p + q * 8 + 4);
            tk2 = *(const float4*)(p + 32 + q * 8);
            tk3 = *(const float4*)(p + 32 + q * 8 + 4);
        }

        // ---- GEMM phase: z[16 x 64w..] = [state|token] . theta^T ----
        f32x4 acc[4];
#pragma unroll
        for (int s = 0; s < 4; ++s) { acc[s][0] = 0.f; acc[s][1] = 0.f; acc[s][2] = 0.f; acc[s][3] = 0.f; }

        const unsigned short* arow = stc + loc * STRD;   // A-frag: lane = row loc
#pragma unroll
        for (int ks = 0; ks < 8; ++ks) {
            bf16x8 av = *(const bf16x8*)(arow + ks * 32 + q * 8);  // ds_read_b128
#pragma unroll
            for (int s = 0; s < 4; ++s)
                acc[s] = __builtin_amdgcn_mfma_f32_16x16x32_bf16(av, bfrag[ks][s], acc[s], 0, 0, 0);
        }
#pragma unroll
        for (int s = 0; s < 4; ++s)
            acc[s] = __builtin_amdgcn_mfma_f32_16x16x32_bf16(a8, bfrag[8][s], acc[s], 0, 0, 0);
#pragma unroll
        for (int s = 0; s < 4; ++s)
            acc[s] = __builtin_amdgcn_mfma_f32_16x16x32_bf16(a9, bfrag[9][s], acc[s], 0, 0, 0);

        // ---- per-row partial stats over this wave's 64 columns ----
        // C layout: acc[s][r] is row q*4+r, col w*64 + s*16 + loc
        float sum[4], ssq[4];
#pragma unroll
        for (int r = 0; r < 4; ++r) {
            sum[r] = acc[0][r] + acc[1][r] + acc[2][r] + acc[3][r];
            ssq[r] = acc[0][r] * acc[0][r] + acc[1][r] * acc[1][r]
                   + acc[2][r] * acc[2][r] + acc[3][r] * acc[3][r];
        }
        // reduce across 16 lanes of the quad-row group: xor1, xor2, ror4, ror8 (DPP)
#pragma unroll
        for (int r = 0; r < 4; ++r) {
            sum[r] = dppadd<0xB1>(sum[r]);  ssq[r] = dppadd<0xB1>(ssq[r]);   // quad_perm 1,0,3,2
            sum[r] = dppadd<0x4E>(sum[r]);  ssq[r] = dppadd<0x4E>(ssq[r]);   // quad_perm 2,3,0,1
            sum[r] = dppadd<0x124>(sum[r]); ssq[r] = dppadd<0x124>(ssq[r]);  // row_ror:4
            sum[r] = dppadd<0x128>(sum[r]); ssq[r] = dppadd<0x128>(ssq[r]);  // row_ror:8
        }
        if (loc < 4)
            partials[((q * 4 + loc) << 2) | w] = make_float2(sum[loc], ssq[loc]);

        __syncthreads();

        // ---- finalize stats (redundant per wave): lane l reads (row l>>2, wave l&3) ----
        float2 pp = partials[l];
        pp.x = dppadd<0xB1>(pp.x); pp.y = dppadd<0xB1>(pp.y);
        pp.x = dppadd<0x4E>(pp.x); pp.y = dppadd<0x4E>(pp.y);
        float mean = pp.x * (1.0f / 256.0f);
        float var  = (pp.y - pp.x * mean) * (1.0f / 255.0f);   // ddof=1 (Bessel)
        float rstd = rsqrtf(var);

        // gather stats for my C-layout rows q*4+r (replicas live in lanes 16q+4r+j)
        float mn[4], rs[4];
#pragma unroll
        for (int r = 0; r < 4; ++r) {
            int src = (l & 48) | (r << 2) | (l & 3);
            mn[r] = __shfl(mean, src, 64);
            rs[r] = __shfl(rstd, src, 64);
        }

        // ---- normalize, relu, write next-state bf16 ----
#pragma unroll
        for (int s = 0; s < 4; ++s) {
#pragma unroll
            for (int r = 0; r < 4; ++r) {
                float v = (acc[s][r] - mn[r]) * rs[r];
                v = fmaxf(v, 0.0f);
                stn[(q * 4 + r) * STRD + (w * 64 + s * 16 + loc)] = f2bf(v);
            }
        }
        __syncthreads();
    }

    // ---- readout: logits = state . theta_dot ; out = sigmoid(logits) ----
    // final state is in buffer (T & 1) ^ 1 == 0
    {
        const int m = tid >> 4, c0 = (tid & 15) << 4;
        const unsigned short* sr = &stbuf[0][m][c0];
        float dot = 0.0f;
#pragma unroll
        for (int j = 0; j < 16; ++j)
            dot += bf2f(sr[j]) * theta_dot[c0 + j];
        dot += __shfl_xor(dot, 1, 64);
        dot += __shfl_xor(dot, 2, 64);
        dot += __shfl_xor(dot, 4, 64);
        dot += __shfl_xor(dot, 8, 64);
        if ((tid & 15) == 0)
            out[r0 + m] = 1.0f / (1.0f + expf(-dot));
    }
}

extern "C" void kernel_launch(void* const* d_in, const int* in_sizes, int n_in,
                              void* d_out, int out_size, void* d_ws, size_t ws_size,
                              hipStream_t stream) {
    const float* seq   = (const float*)d_in[0];  // [2048*512*64]
    const float* theta = (const float*)d_in[1];  // [256*320]
    // d_in[2] = bias[1]: constant shift cancels exactly in LayerNorm -> unused
    const float* tdot  = (const float*)d_in[3];  // [256]
    float* out = (float*)d_out;

    rnn_scan_kernel<<<dim3(128), dim3(256), 0, stream>>>(seq, theta, tdot, out);
}

// Round 2
// 854.171 us; speedup vs baseline: 1.0697x; 1.0697x over previous
//
#include <hip/hip_runtime.h>

// RNN scan: B=2048, T=512, V=64, H=256, K=H+V=320.
// 128 persistent blocks x 256 threads (4 waves). Each block owns 16 batch rows
// for all 512 steps. Theta lives in VGPRs as MFMA B-fragments (loaded once).
// State double-buffered in LDS as bf16. Tokens stream global->VGPR in A-frag
// layout, prefetched one step ahead.
// R2: raw s_barrier with lgkmcnt-only drain (compiler's __syncthreads drains
// vmcnt(0), exposing the token prefetch's ~900cy HBM latency every step);
// stage-2 LN stats via b128 broadcast-read + quad_perm DPP (no ds_bpermute);
// 2-op bf16 round; fma normalize.

#define TT 512
#define VV 64
#define HH 256
#define STRD 264   // ushorts per state row: 256 + 8 pad (33 x 16B -> conflict-free b128)

typedef short bf16x8 __attribute__((ext_vector_type(8)));
typedef float f32x4  __attribute__((ext_vector_type(4)));

__device__ __forceinline__ unsigned short f2bf(float f) {
    unsigned int u = __float_as_uint(f);
    return (unsigned short)((u + 0x8000u) >> 16);   // round-to-nearest (no tie fix)
}

__device__ __forceinline__ float bf2f(unsigned short u) {
    return __uint_as_float(((unsigned int)u) << 16);
}

__device__ __forceinline__ bf16x8 pack8(float4 a, float4 b) {
    bf16x8 v;
    v[0] = (short)f2bf(a.x); v[1] = (short)f2bf(a.y);
    v[2] = (short)f2bf(a.z); v[3] = (short)f2bf(a.w);
    v[4] = (short)f2bf(b.x); v[5] = (short)f2bf(b.y);
    v[6] = (short)f2bf(b.z); v[7] = (short)f2bf(b.w);
    return v;
}

// x += dpp_perm(x); CTRL compile-time. VALU pipe (keeps LDS pipe free).
template <int CTRL>
__device__ __forceinline__ float dppadd(float x) {
    int y = __builtin_amdgcn_update_dpp(0, __float_as_int(x), CTRL, 0xF, 0xF, false);
    return x + __int_as_float(y);
}

// quad_perm broadcast: lanes 4a..4a+3 <- lane 4a + r (CTRL = rrrr pattern)
template <int CTRL>
__device__ __forceinline__ float dppbcast(float x) {
    int y = __builtin_amdgcn_update_dpp(0, __float_as_int(x), CTRL, 0xF, 0xF, true);
    return __int_as_float(y);
}

// s_barrier with LDS-only drain: do NOT drain vmcnt (keeps token prefetch in
// flight across the barrier). LDS visibility needs lgkmcnt(0) only.
__device__ __forceinline__ void barrier_lgkm() {
    asm volatile("s_waitcnt lgkmcnt(0)\n\ts_barrier" ::: "memory");
}

extern "C" __global__ void __launch_bounds__(256, 1)
rnn_scan_kernel(const float* __restrict__ seq,        // [2048][512][64]
                const float* __restrict__ theta,      // [256][320]
                const float* __restrict__ theta_dot,  // [256]
                float* __restrict__ out)              // [2048]
{
    __shared__ unsigned short stbuf[2][16][STRD];        // state, bf16, double-buffered
    __shared__ __align__(16) float2 partials[64];        // [row 0..15][wave 0..3] (sum, sumsq)

    const int tid = threadIdx.x;
    const int w   = tid >> 6;        // wave 0..3  -> N columns [64w, 64w+64)
    const int l   = tid & 63;        // lane
    const int q   = l >> 4;          // quad-row group 0..3
    const int loc = l & 15;
    const int r0  = blockIdx.x << 4; // first batch row of this block

    // ---- Theta -> resident B-fragments: bfrag[ks][s] covers K [32ks,32ks+32) x N [64w+16s, +16)
    bf16x8 bfrag[10][4];
#pragma unroll
    for (int s = 0; s < 4; ++s) {
        const float* trow = theta + (size_t)(w * 64 + s * 16 + loc) * 320;
#pragma unroll
        for (int ks = 0; ks < 10; ++ks) {
            float4 f0 = *(const float4*)(trow + ks * 32 + q * 8);
            float4 f1 = *(const float4*)(trow + ks * 32 + q * 8 + 4);
            bfrag[ks][s] = pack8(f0, f1);
        }
    }

    // ---- zero initial state (buffer 0) ----
    {
        const int m = tid >> 4, c = (tid & 15) * 16;
        uint4 z = make_uint4(0u, 0u, 0u, 0u);
        *(uint4*)(&stbuf[0][m][c])     = z;
        *(uint4*)(&stbuf[0][m][c + 8]) = z;
    }

    // ---- prefetch token t=0 in A-frag layout: lane = row loc, features q*8.. ----
    const float* srow = seq + (size_t)(r0 + loc) * (TT * VV);
    float4 tk0 = *(const float4*)(srow + q * 8);
    float4 tk1 = *(const float4*)(srow + q * 8 + 4);
    float4 tk2 = *(const float4*)(srow + 32 + q * 8);
    float4 tk3 = *(const float4*)(srow + 32 + q * 8 + 4);

    __syncthreads();

#pragma unroll 1
    for (int t = 0; t < TT; ++t) {
        unsigned short* stc = &stbuf[t & 1][0][0];
        unsigned short* stn = &stbuf[(t + 1) & 1][0][0];

        // token A-frags for this step (K blocks 8,9 = features 0..31 / 32..63)
        bf16x8 a8 = pack8(tk0, tk1);
        bf16x8 a9 = pack8(tk2, tk3);

        // prefetch next step's token; with raw barriers this stays in flight
        // until the pack8 at the top of the next iteration (full-step cover)
        if (t + 1 < TT) {
            const float* p = srow + (size_t)(t + 1) * VV;
            tk0 = *(const float4*)(p + q * 8);
            tk1 = *(const float4*)(p + q * 8 + 4);
            tk2 = *(const float4*)(p + 32 + q * 8);
            tk3 = *(const float4*)(p + 32 + q * 8 + 4);
        }

        // ---- GEMM phase: z[16 x 64w..] = [state|token] . theta^T ----
        f32x4 acc[4];
#pragma unroll
        for (int s = 0; s < 4; ++s) { acc[s][0] = 0.f; acc[s][1] = 0.f; acc[s][2] = 0.f; acc[s][3] = 0.f; }

        const unsigned short* arow = stc + loc * STRD;   // A-frag: lane = row loc
#pragma unroll
        for (int ks = 0; ks < 8; ++ks) {
            bf16x8 av = *(const bf16x8*)(arow + ks * 32 + q * 8);  // ds_read_b128
#pragma unroll
            for (int s = 0; s < 4; ++s)
                acc[s] = __builtin_amdgcn_mfma_f32_16x16x32_bf16(av, bfrag[ks][s], acc[s], 0, 0, 0);
        }
#pragma unroll
        for (int s = 0; s < 4; ++s)
            acc[s] = __builtin_amdgcn_mfma_f32_16x16x32_bf16(a8, bfrag[8][s], acc[s], 0, 0, 0);
#pragma unroll
        for (int s = 0; s < 4; ++s)
            acc[s] = __builtin_amdgcn_mfma_f32_16x16x32_bf16(a9, bfrag[9][s], acc[s], 0, 0, 0);

        // ---- per-row partial stats over this wave's 64 columns ----
        // C layout: acc[s][r] is row q*4+r, col w*64 + s*16 + loc
        float sum[4], ssq[4];
#pragma unroll
        for (int r = 0; r < 4; ++r) {
            sum[r] = acc[0][r] + acc[1][r] + acc[2][r] + acc[3][r];
            ssq[r] = acc[0][r] * acc[0][r] + acc[1][r] * acc[1][r]
                   + acc[2][r] * acc[2][r] + acc[3][r] * acc[3][r];
        }
        // reduce across 16 lanes of the quad-row group: xor1, xor2, ror4, ror8 (DPP)
#pragma unroll
        for (int r = 0; r < 4; ++r) {
            sum[r] = dppadd<0xB1>(sum[r]);  ssq[r] = dppadd<0xB1>(ssq[r]);   // quad_perm 1,0,3,2
            sum[r] = dppadd<0x4E>(sum[r]);  ssq[r] = dppadd<0x4E>(ssq[r]);   // quad_perm 2,3,0,1
            sum[r] = dppadd<0x124>(sum[r]); ssq[r] = dppadd<0x124>(ssq[r]);  // row_ror:4
            sum[r] = dppadd<0x128>(sum[r]); ssq[r] = dppadd<0x128>(ssq[r]);  // row_ror:8
        }
        if (loc < 4)
            partials[((q * 4 + loc) << 2) | w] = make_float2(sum[loc], ssq[loc]);

        barrier_lgkm();

        // ---- finalize stats: lane handles row q*4+(loc&3); 4 lanes redundant ----
        // partials[row][0..3] = 32B contiguous -> two b128 broadcast reads
        const int myrow = (q << 2) | (loc & 3);
        float4 pA = *(const float4*)(&partials[myrow << 2]);       // waves 0,1
        float4 pB = *(const float4*)(&partials[(myrow << 2) | 2]); // waves 2,3
        float sumT = (pA.x + pA.z) + (pB.x + pB.z);
        float ssqT = (pA.y + pA.w) + (pB.y + pB.w);
        float mean = sumT * (1.0f / 256.0f);
        float var  = (ssqT - sumT * mean) * (1.0f / 255.0f);   // ddof=1 (Bessel)
        float rstd = rsqrtf(var);
        float nb   = -mean * rstd;                              // v = fma(z, rstd, nb)

        // broadcast (rstd, nb) for rows q*4+r to all lanes of each nibble (VALU DPP)
        float rs[4], nbv[4];
        rs[0] = dppbcast<0x00>(rstd); nbv[0] = dppbcast<0x00>(nb);
        rs[1] = dppbcast<0x55>(rstd); nbv[1] = dppbcast<0x55>(nb);
        rs[2] = dppbcast<0xAA>(rstd); nbv[2] = dppbcast<0xAA>(nb);
        rs[3] = dppbcast<0xFF>(rstd); nbv[3] = dppbcast<0xFF>(nb);

        // ---- normalize, relu, write next-state bf16 ----
#pragma unroll
        for (int s = 0; s < 4; ++s) {
#pragma unroll
            for (int r = 0; r < 4; ++r) {
                float v = fmaf(acc[s][r], rs[r], nbv[r]);
                v = fmaxf(v, 0.0f);
                stn[(q * 4 + r) * STRD + (w * 64 + s * 16 + loc)] = f2bf(v);
            }
        }
        barrier_lgkm();
    }

    // ---- readout: logits = state . theta_dot ; out = sigmoid(logits) ----
    // final state is in buffer (T & 1) ^ 1 == 0
    {
        const int m = tid >> 4, c0 = (tid & 15) << 4;
        const unsigned short* sr = &stbuf[0][m][c0];
        float dot = 0.0f;
#pragma unroll
        for (int j = 0; j < 16; ++j)
            dot += bf2f(sr[j]) * theta_dot[c0 + j];
        dot += __shfl_xor(dot, 1, 64);
        dot += __shfl_xor(dot, 2, 64);
        dot += __shfl_xor(dot, 4, 64);
        dot += __shfl_xor(dot, 8, 64);
        if ((tid & 15) == 0)
            out[r0 + m] = 1.0f / (1.0f + expf(-dot));
    }
}

extern "C" void kernel_launch(void* const* d_in, const int* in_sizes, int n_in,
                              void* d_out, int out_size, void* d_ws, size_t ws_size,
                              hipStream_t stream) {
    const float* seq   = (const float*)d_in[0];  // [2048*512*64]
    const float* theta = (const float*)d_in[1];  // [256*320]
    // d_in[2] = bias[1]: constant shift cancels exactly in LayerNorm -> unused
    const float* tdot  = (const float*)d_in[3];  // [256]
    float* out = (float*)d_out;

    rnn_scan_kernel<<<dim3(128), dim3(256), 0, stream>>>(seq, theta, tdot, out);
}